// Round 1
// baseline (726.406 us; speedup 1.0000x reference)
//
#include <hip/hip_runtime.h>
#include <hip/hip_bf16.h>
#include <float.h>
#include <stdint.h>

// Forbid FMA contraction globally: the reference (numpy/XLA fp32) computes
// each mul/add as a separately-rounded op; a fused (a1+a2)-iw*ih could flip
// an iou>0.5 decision and swap a selected box (absmax ~1000 vs thr 19.9).
#pragma clang fp contract(off)

#define NEGV   (-1e9f)
#define THRV   (0.05f)
#define IOUT   (0.5f)
#define MAXDET 100

__device__ __forceinline__ void amax2(float& v, int& i, float ov, int oi) {
  // lexicographic: higher value wins; equal value -> lower index wins
  if (ov > v || (ov == v && oi < i)) { v = ov; i = oi; }
}

// One block per (image, class). Each thread owns K boxes fully in registers.
// 100 iterations of {global argmax, broadcast best box, suppress by IoU}.
template<int K, int BT>
__global__ __launch_bounds__(BT, 1) void nms_kernel(
    const float* __restrict__ boxes, const float* __restrict__ cls,
    float* __restrict__ ksc, float* __restrict__ kbx, int N, int C)
{
#pragma clang fp contract(off)
  const int bc = blockIdx.x;
  const int b = bc / C, c = bc % C;
  const int tid = threadIdx.x;
  const int lane = tid & 63, wid = tid >> 6;

  float sc[K], px1[K], py1[K], px2[K], py2[K], ar[K];
  const float* bb = boxes + (size_t)b * N * 4;
  const float* cp = cls + (size_t)b * N * C + c;
#pragma unroll
  for (int k = 0; k < K; ++k) {
    const int i = tid + k * BT;
    if (i < N) {
      const float s = cp[(size_t)i * C];
      sc[k] = (s > THRV) ? s : NEGV;
      const float4 v = *reinterpret_cast<const float4*>(bb + (size_t)i * 4);
      px1[k] = v.x; py1[k] = v.y; px2[k] = v.z; py2[k] = v.w;
      ar[k] = (v.z - v.x) * (v.w - v.y);
    } else {
      sc[k] = NEGV; px1[k] = 0.f; py1[k] = 0.f; px2[k] = 0.f; py2[k] = 0.f;
      ar[k] = 0.f;
    }
  }

  __shared__ float red_v[BT / 64];
  __shared__ int   red_i[BT / 64];
  __shared__ float bbx[4];

  float* ko  = ksc + (size_t)bc * MAXDET;
  float* kbo = kbx + (size_t)bc * MAXDET * 4;

  for (int m = 0; m < MAXDET; ++m) {
    // --- local argmax over register slots (indices ascending -> strict >) ---
    float bv = sc[0]; int bi = tid;
#pragma unroll
    for (int k = 1; k < K; ++k)
      if (sc[k] > bv) { bv = sc[k]; bi = tid + k * BT; }
    // --- wave64 butterfly ---
#pragma unroll
    for (int off = 32; off >= 1; off >>= 1) {
      const float ov = __shfl_xor(bv, off, 64);
      const int   oi = __shfl_xor(bi, off, 64);
      amax2(bv, bi, ov, oi);
    }
    if (lane == 0) { red_v[wid] = bv; red_i[wid] = bi; }
    __syncthreads();   // barrier 1: red[] written -> read
    {
      const int nw = BT / 64;
      const int j = lane & (nw - 1);
      bv = red_v[j]; bi = red_i[j];
#pragma unroll
      for (int off = nw / 2; off >= 1; off >>= 1) {
        const float ov = __shfl_xor(bv, off, 64);
        const int   oi = __shfl_xor(bi, off, 64);
        amax2(bv, bi, ov, oi);
      }
    }
    // every thread now holds the global (bv, bi); bv is uniform
    if (bv <= THRV) {
      // nothing valid remains: remaining reference slots are (NEG, boxes[0])
      // and get masked to -1 downstream; score NEG + any box reproduces that.
      for (int mm = m + tid; mm < MAXDET; mm += BT) {
        ko[mm] = NEGV;
        kbo[mm * 4 + 0] = 0.f; kbo[mm * 4 + 1] = 0.f;
        kbo[mm * 4 + 2] = 0.f; kbo[mm * 4 + 3] = 0.f;
      }
      return;
    }
    // --- owner broadcasts the selected box via LDS (static reg indexing) ---
    if ((bi & (BT - 1)) == tid) {
      const int kk = bi / BT;
      float ox1 = 0.f, oy1 = 0.f, ox2 = 0.f, oy2 = 0.f;
#pragma unroll
      for (int k = 0; k < K; ++k)
        if (k == kk) { ox1 = px1[k]; oy1 = py1[k]; ox2 = px2[k]; oy2 = py2[k]; }
      bbx[0] = ox1; bbx[1] = oy1; bbx[2] = ox2; bbx[3] = oy2;
    }
    __syncthreads();   // barrier 2: bbx written -> read (also fences red[])
    const float qx1 = bbx[0], qy1 = bbx[1], qx2 = bbx[2], qy2 = bbx[3];
    const float a1 = (qx2 - qx1) * (qy2 - qy1);
    if (tid == 0) {
      ko[m] = bv;
      kbo[m * 4 + 0] = qx1; kbo[m * 4 + 1] = qy1;
      kbo[m * 4 + 2] = qx2; kbo[m * 4 + 3] = qy2;
    }
    // --- suppress own boxes; exact reference op order, IEEE fp32 div ---
#pragma unroll
    for (int k = 0; k < K; ++k) {
      const float ix1 = fmaxf(qx1, px1[k]);
      const float iy1 = fmaxf(qy1, py1[k]);
      const float ix2 = fminf(qx2, px2[k]);
      const float iy2 = fminf(qy2, py2[k]);
      const float iw = fmaxf(ix2 - ix1, 0.f);
      const float ih = fmaxf(iy2 - iy1, 0.f);
      const float inter = iw * ih;
      const float den = fmaxf((a1 + ar[k]) - inter, 1e-8f);
      const float iou = inter / den;
      if (iou > IOUT) sc[k] = NEGV;
    }
    // no barrier needed here: next red[] write is fenced by barrier 2,
    // next bbx write is fenced by next iteration's barrier 1.
  }
}

// One block per image: stable top-100 of C*100 scores via repeated argmax
// with (value desc, flat-index asc) order == lax.top_k tie semantics.
template<int E, int BT>
__global__ __launch_bounds__(BT, 1) void topk_kernel(
    const float* __restrict__ ksc, const float* __restrict__ kbx,
    float* __restrict__ out, int B, int C)
{
#pragma clang fp contract(off)
  const int b = blockIdx.x;
  const int tid = threadIdx.x;
  const int lane = tid & 63, wid = tid >> 6;
  const int T = C * MAXDET;

  float sc[E];
  const float* s0 = ksc + (size_t)b * T;
#pragma unroll
  for (int e = 0; e < E; ++e) {
    const int i = tid + e * BT;
    sc[e] = (i < T) ? s0[i] : -FLT_MAX;
  }

  __shared__ float red_v[BT / 64];
  __shared__ int   red_i[BT / 64];

  float* ob = out;                            // [B][100][4]
  float* os = out + (size_t)B * MAXDET * 4;   // [B][100]
  float* ol = os + (size_t)B * MAXDET;        // [B][100] labels as float

  for (int m = 0; m < MAXDET; ++m) {
    float bv = sc[0]; int bi = tid;
#pragma unroll
    for (int e = 1; e < E; ++e)
      if (sc[e] > bv) { bv = sc[e]; bi = tid + e * BT; }
#pragma unroll
    for (int off = 32; off >= 1; off >>= 1) {
      const float ov = __shfl_xor(bv, off, 64);
      const int   oi = __shfl_xor(bi, off, 64);
      amax2(bv, bi, ov, oi);
    }
    if (lane == 0) { red_v[wid] = bv; red_i[wid] = bi; }
    __syncthreads();
    {
      const int nw = BT / 64;
      const int j = lane & (nw - 1);
      bv = red_v[j]; bi = red_i[j];
#pragma unroll
      for (int off = nw / 2; off >= 1; off >>= 1) {
        const float ov = __shfl_xor(bv, off, 64);
        const int   oi = __shfl_xor(bi, off, 64);
        amax2(bv, bi, ov, oi);
      }
    }
    // owner marks selected slot as taken (below NEG so it never re-wins)
    if ((bi & (BT - 1)) == tid) {
      const int kk = bi / BT;
#pragma unroll
      for (int e = 0; e < E; ++e)
        if (e == kk) sc[e] = -FLT_MAX;
    }
    if (tid == 0) {
      const bool valid = bv > THRV;
      const int f = bi;                       // = class*100 + slot
      const float* bp = kbx + ((size_t)b * T + f) * 4;
      const float o0 = valid ? bp[0] : -1.f;
      const float o1 = valid ? bp[1] : -1.f;
      const float o2 = valid ? bp[2] : -1.f;
      const float o3 = valid ? bp[3] : -1.f;
      float* od = ob + ((size_t)b * MAXDET + m) * 4;
      od[0] = o0; od[1] = o1; od[2] = o2; od[3] = o3;
      os[(size_t)b * MAXDET + m] = valid ? bv : -1.f;
      ol[(size_t)b * MAXDET + m] = valid ? (float)(f / MAXDET) : -1.f;
    }
    __syncthreads();   // fence red[] reads vs next iteration's writes
  }
}

extern "C" void kernel_launch(void* const* d_in, const int* in_sizes, int n_in,
                              void* d_out, int out_size, void* d_ws, size_t ws_size,
                              hipStream_t stream) {
  const float* boxes = (const float*)d_in[0];  // (B, N, 4) f32
  const float* cls   = (const float*)d_in[1];  // (B, N, C) f32
  const int B = out_size / (MAXDET * 6);       // 4 box + 1 score + 1 label
  const int N = in_sizes[0] / (B * 4);
  const int C = in_sizes[1] / (B * N);

  float* ksc = (float*)d_ws;                         // [B*C][100] scores
  float* kbx = ksc + (size_t)B * C * MAXDET;         // [B*C][100][4] boxes

  nms_kernel<10, 1024><<<dim3(B * C), dim3(1024), 0, stream>>>(
      boxes, cls, ksc, kbx, N, C);
  topk_kernel<8, 1024><<<dim3(B), dim3(1024), 0, stream>>>(
      ksc, kbx, (float*)d_out, B, C);
}

// Round 2
// 466.107 us; speedup vs baseline: 1.5585x; 1.5585x over previous
//
#include <hip/hip_runtime.h>
#include <hip/hip_bf16.h>
#include <float.h>
#include <stdint.h>

// Forbid FMA contraction: reference (numpy fp32) rounds every mul/add
// separately; a fused (a1+a2)-iw*ih could flip an iou>0.5 decision.
#pragma clang fp contract(off)

#define NEGV   (-1e9f)
#define THRV   (0.05f)
#define MAXDET 100

__device__ __forceinline__ void amax2(float& v, int& i, float ov, int oi) {
  // lexicographic: higher value wins; equal value -> lower index wins
  if (ov > v || (ov == v && oi < i)) { v = ov; i = oi; }
}

// monotone float->u32 map (total order preserved): negatives below positives
__device__ __forceinline__ unsigned mapf(float v) {
  const unsigned u = __float_as_uint(v);
  return (u & 0x80000000u) ? ~u : (u | 0x80000000u);
}
__device__ __forceinline__ float unmapf(unsigned m) {
  const unsigned u = (m & 0x80000000u) ? (m & 0x7FFFFFFFu) : ~m;
  return __uint_as_float(u);
}

// Bit-exact "(inter/den) > 0.5" without paying the IEEE divide in the
// common case. t = den*0.5 is exact (den >= 1e-8, no denormal scaling).
// If inter clears t*(1+1e-5) the rounded quotient is certainly > 0.5;
// if it's below t*(1-1e-5) it certainly isn't; only the ~1e-7-probability
// window does the exact reference divide.
__device__ __forceinline__ bool iou_gt_half(float inter, float den) {
  const float t = den * 0.5f;
  if (inter > t * 1.00001f) return true;
  if (inter < t * 0.99999f) return false;
  return (inter / den) > 0.5f;
}

// ---------------------------------------------------------------------------
// Kernel 1: per-(image,class) stable compaction of scores > 0.05.
// Order-preserving => compacted position order == original index order,
// so downstream tie-breaks on compacted position match jnp.argmax.
// ---------------------------------------------------------------------------
template<int BT>
__global__ __launch_bounds__(BT, 1) void compact_kernel(
    const float* __restrict__ cls, int* __restrict__ cnt,
    float* __restrict__ cscore, int* __restrict__ cidx, int N, int C)
{
  const int bc = blockIdx.x;
  const int b = bc / C, c = bc % C;
  const int tid = threadIdx.x, lane = tid & 63, wid = tid >> 6;
  const int chunk = (N + BT - 1) / BT;
  const int i0 = tid * chunk;
  const int i1 = min(N, i0 + chunk);
  const float* cp = cls + (size_t)b * N * C + c;

  int cntt = 0;
  for (int i = i0; i < i1; ++i) cntt += (cp[(size_t)i * C] > THRV) ? 1 : 0;

  // wave-inclusive scan of per-thread counts
  int inc = cntt;
#pragma unroll
  for (int off = 1; off < 64; off <<= 1) {
    const int u = __shfl_up(inc, off, 64);
    if (lane >= off) inc += u;
  }
  __shared__ int wtot[BT / 64];
  if (lane == 63) wtot[wid] = inc;
  __syncthreads();
  int base = 0;
  for (int w = 0; w < wid; ++w) base += wtot[w];
  int pos = base + inc - cntt;   // exclusive prefix for this thread

  for (int i = i0; i < i1; ++i) {
    const float s = cp[(size_t)i * C];
    if (s > THRV) {
      cscore[(size_t)bc * N + pos] = s;
      cidx[(size_t)bc * N + pos] = i;
      ++pos;
    }
  }
  if (tid == BT - 1) cnt[bc] = base + inc;
}

// ---------------------------------------------------------------------------
// Kernel 2: register-resident greedy NMS over the compacted alive set.
// One block per (image,class); handles cn <= KM*BT (else fallback kernel).
// ---------------------------------------------------------------------------
template<int KM, int BT>
__global__ __launch_bounds__(BT, 1) void nms_kernel(
    const float* __restrict__ boxes, const int* __restrict__ cnt,
    const float* __restrict__ cscore, const int* __restrict__ cidx,
    float* __restrict__ ksc, float* __restrict__ kbx, int N, int C)
{
#pragma clang fp contract(off)
  const int bc = blockIdx.x;
  const int cn = cnt[bc];
  if (cn > KM * BT) return;           // fallback kernel owns this block
  const int b = bc / C;
  const int tid = threadIdx.x, lane = tid & 63, wid = tid >> 6;
  constexpr int NW = BT / 64;

  float sc[KM], px1[KM], py1[KM], px2[KM], py2[KM], ar[KM];
  const float* bb = boxes + (size_t)b * N * 4;
  const float* cs = cscore + (size_t)bc * N;
  const int*   ci = cidx   + (size_t)bc * N;

  float bv = NEGV; int bi = 0x7FFFFFFF;
#pragma unroll
  for (int k = 0; k < KM; ++k) {
    const int p = tid + k * BT;
    sc[k] = NEGV; px1[k] = 0.f; py1[k] = 0.f; px2[k] = 0.f; py2[k] = 0.f;
    ar[k] = 0.f;
    if (p < cn) {
      const float s = cs[p];
      const int id = ci[p];
      const float4 v = *reinterpret_cast<const float4*>(bb + (size_t)id * 4);
      sc[k] = s; px1[k] = v.x; py1[k] = v.y; px2[k] = v.z; py2[k] = v.w;
      ar[k] = (v.z - v.x) * (v.w - v.y);
      if (s > bv) { bv = s; bi = p; }   // p ascending in k => first-max
    }
  }

  __shared__ unsigned long long red[NW];
  __shared__ float bbx[4];
  float* ko  = ksc + (size_t)bc * MAXDET;
  float* kbo = kbx + (size_t)bc * MAXDET * 4;

  for (int m = 0; m < MAXDET; ++m) {
    // wave butterfly on (value, compacted index)
#pragma unroll
    for (int off = 32; off >= 1; off >>= 1) {
      const float ov = __shfl_xor(bv, off, 64);
      const int   oi = __shfl_xor(bi, off, 64);
      amax2(bv, bi, ov, oi);
    }
    if (lane == 0)
      red[wid] = ((unsigned long long)mapf(bv) << 32) | (unsigned)~bi;
    __syncthreads();                   // barrier 1: red written -> read
    unsigned long long best = red[0];
#pragma unroll
    for (int w = 1; w < NW; ++w) {
      const unsigned long long o = red[w];
      if (o > best) best = o;          // (value desc, index asc) by packing
    }
    bv = unmapf((unsigned)(best >> 32));
    bi = (int)(~(unsigned)best);

    if (bv <= THRV) {                  // uniform: nothing valid remains
      for (int mm = m + tid; mm < MAXDET; mm += BT) {
        ko[mm] = NEGV;
        kbo[mm * 4 + 0] = 0.f; kbo[mm * 4 + 1] = 0.f;
        kbo[mm * 4 + 2] = 0.f; kbo[mm * 4 + 3] = 0.f;
      }
      return;
    }
    // owner broadcasts the winning box (static reg indexing)
    if ((bi & (BT - 1)) == tid) {
      const int kk = bi / BT;
      float ox1 = 0.f, oy1 = 0.f, ox2 = 0.f, oy2 = 0.f;
#pragma unroll
      for (int k = 0; k < KM; ++k)
        if (k == kk) { ox1 = px1[k]; oy1 = py1[k]; ox2 = px2[k]; oy2 = py2[k]; }
      bbx[0] = ox1; bbx[1] = oy1; bbx[2] = ox2; bbx[3] = oy2;
    }
    __syncthreads();                   // barrier 2: bbx ready (fences red WAR)
    const float qx1 = bbx[0], qy1 = bbx[1], qx2 = bbx[2], qy2 = bbx[3];
    const float a1 = (qx2 - qx1) * (qy2 - qy1);
    if (tid == 0) {
      ko[m] = bv;
      kbo[m * 4 + 0] = qx1; kbo[m * 4 + 1] = qy1;
      kbo[m * 4 + 2] = qx2; kbo[m * 4 + 3] = qy2;
    }
    // fused suppress + next-iteration local argmax (exact reference op order)
    bv = NEGV; bi = 0x7FFFFFFF;
#pragma unroll
    for (int k = 0; k < KM; ++k) {
      const int p = tid + k * BT;
      if (p < cn) {
        const float ix1 = fmaxf(qx1, px1[k]);
        const float iy1 = fmaxf(qy1, py1[k]);
        const float ix2 = fminf(qx2, px2[k]);
        const float iy2 = fminf(qy2, py2[k]);
        const float iw = fmaxf(ix2 - ix1, 0.f);
        const float ih = fmaxf(iy2 - iy1, 0.f);
        const float inter = iw * ih;
        const float den = fmaxf((a1 + ar[k]) - inter, 1e-8f);
        if (iou_gt_half(inter, den)) sc[k] = NEGV;
        const float s = sc[k];
        if (s > bv) { bv = s; bi = p; }
      }
    }
  }
}

// ---------------------------------------------------------------------------
// Kernel 2b: global-resident fallback for cn > cap (correctness safety net;
// never runs for the bench shapes). Scores mutate in cscore; each thread
// owns p = tid (mod BT) slots, so no cross-thread score communication.
// ---------------------------------------------------------------------------
template<int BT>
__global__ __launch_bounds__(BT, 1) void nms_fallback_kernel(
    const float* __restrict__ boxes, const int* __restrict__ cnt,
    float* __restrict__ cscore, const int* __restrict__ cidx,
    float* __restrict__ ksc, float* __restrict__ kbx, int N, int C, int cap)
{
#pragma clang fp contract(off)
  const int bc = blockIdx.x;
  const int cn = cnt[bc];
  if (cn <= cap) return;
  const int b = bc / C;
  const int tid = threadIdx.x, lane = tid & 63, wid = tid >> 6;
  constexpr int NW = BT / 64;
  const float* bb = boxes + (size_t)b * N * 4;
  float* cs = cscore + (size_t)bc * N;
  const int* ci = cidx + (size_t)bc * N;
  __shared__ unsigned long long red[NW];
  float* ko  = ksc + (size_t)bc * MAXDET;
  float* kbo = kbx + (size_t)bc * MAXDET * 4;

  for (int m = 0; m < MAXDET; ++m) {
    float bv = NEGV; int bi = 0x7FFFFFFF;
    for (int p = tid; p < cn; p += BT) {
      const float s = cs[p];
      if (s > bv) { bv = s; bi = p; }
    }
#pragma unroll
    for (int off = 32; off >= 1; off >>= 1) {
      const float ov = __shfl_xor(bv, off, 64);
      const int   oi = __shfl_xor(bi, off, 64);
      amax2(bv, bi, ov, oi);
    }
    if (lane == 0)
      red[wid] = ((unsigned long long)mapf(bv) << 32) | (unsigned)~bi;
    __syncthreads();
    unsigned long long best = red[0];
#pragma unroll
    for (int w = 1; w < NW; ++w) {
      const unsigned long long o = red[w];
      if (o > best) best = o;
    }
    bv = unmapf((unsigned)(best >> 32));
    bi = (int)(~(unsigned)best);
    __syncthreads();                   // WAR fence for red

    if (bv <= THRV) {
      for (int mm = m + tid; mm < MAXDET; mm += BT) {
        ko[mm] = NEGV;
        kbo[mm * 4 + 0] = 0.f; kbo[mm * 4 + 1] = 0.f;
        kbo[mm * 4 + 2] = 0.f; kbo[mm * 4 + 3] = 0.f;
      }
      return;
    }
    const int qid = ci[bi];
    const float4 q = *reinterpret_cast<const float4*>(bb + (size_t)qid * 4);
    const float a1 = (q.z - q.x) * (q.w - q.y);
    if (tid == 0) {
      ko[m] = bv;
      kbo[m * 4 + 0] = q.x; kbo[m * 4 + 1] = q.y;
      kbo[m * 4 + 2] = q.z; kbo[m * 4 + 3] = q.w;
    }
    for (int p = tid; p < cn; p += BT) {
      const float s = cs[p];
      if (s > NEGV) {
        const int id = ci[p];
        const float4 v = *reinterpret_cast<const float4*>(bb + (size_t)id * 4);
        const float ix1 = fmaxf(q.x, v.x);
        const float iy1 = fmaxf(q.y, v.y);
        const float ix2 = fminf(q.z, v.z);
        const float iy2 = fminf(q.w, v.w);
        const float iw = fmaxf(ix2 - ix1, 0.f);
        const float ih = fmaxf(iy2 - iy1, 0.f);
        const float inter = iw * ih;
        const float a2 = (v.z - v.x) * (v.w - v.y);
        const float den = fmaxf((a1 + a2) - inter, 1e-8f);
        if (iou_gt_half(inter, den)) cs[p] = NEGV;
      }
    }
  }
}

// ---------------------------------------------------------------------------
// Kernel 3: per-image top-100 as an 80-way merge of the per-class
// descending keep_score lists. Single wave, no barriers.
// Tie semantics == lax.top_k: (value desc, flat index asc).
// Assumes C <= 128.
// ---------------------------------------------------------------------------
__global__ __launch_bounds__(64, 1) void topk_kernel(
    const float* __restrict__ ksc, const float* __restrict__ kbx,
    float* __restrict__ out, int B, int C)
{
  const int b = blockIdx.x;
  const int lane = threadIdx.x;
  const int T = C * MAXDET;
  const float* s0 = ksc + (size_t)b * T;
  float* ob = out;                              // [B][100][4]
  float* os = out + (size_t)B * MAXDET * 4;     // [B][100]
  float* ol = os + (size_t)B * MAXDET;          // [B][100] labels as float

  int h0 = 0, h1 = 0;
  const int c0 = lane;
  const int c1 = lane + 64;

  for (int m = 0; m < MAXDET; ++m) {
    float bv = -FLT_MAX; int bf = 0x7FFFFFFF;
    if (c0 < C && h0 < MAXDET) {
      const float v = s0[c0 * MAXDET + h0];
      amax2(bv, bf, v, c0 * MAXDET + h0);
    }
    if (c1 < C && h1 < MAXDET) {
      const float v = s0[c1 * MAXDET + h1];
      amax2(bv, bf, v, c1 * MAXDET + h1);
    }
#pragma unroll
    for (int off = 32; off >= 1; off >>= 1) {
      const float ov = __shfl_xor(bv, off, 64);
      const int   of = __shfl_xor(bf, off, 64);
      amax2(bv, bf, ov, of);
    }
    if (bv <= THRV) {                 // all remaining invalid -> fill -1
      for (int mm = m + lane; mm < MAXDET; mm += 64) {
        float* od = ob + ((size_t)b * MAXDET + mm) * 4;
        od[0] = -1.f; od[1] = -1.f; od[2] = -1.f; od[3] = -1.f;
        os[(size_t)b * MAXDET + mm] = -1.f;
        ol[(size_t)b * MAXDET + mm] = -1.f;
      }
      return;
    }
    const int wc = bf / MAXDET;       // winning class
    if (lane == (wc & 63)) { if (wc < 64) ++h0; else ++h1; }
    if (lane == 0) {
      const float* bp = kbx + ((size_t)b * T + bf) * 4;
      float* od = ob + ((size_t)b * MAXDET + m) * 4;
      od[0] = bp[0]; od[1] = bp[1]; od[2] = bp[2]; od[3] = bp[3];
      os[(size_t)b * MAXDET + m] = bv;
      ol[(size_t)b * MAXDET + m] = (float)wc;
    }
  }
}

extern "C" void kernel_launch(void* const* d_in, const int* in_sizes, int n_in,
                              void* d_out, int out_size, void* d_ws, size_t ws_size,
                              hipStream_t stream) {
  const float* boxes = (const float*)d_in[0];  // (B, N, 4) f32
  const float* cls   = (const float*)d_in[1];  // (B, N, C) f32
  const int B = out_size / (MAXDET * 6);       // 4 box + 1 score + 1 label
  const int N = in_sizes[0] / (B * 4);
  const int C = in_sizes[1] / (B * N);

  char* ws = (char*)d_ws;
  float* ksc = (float*)ws;    ws += (size_t)B * C * MAXDET * 4;        // scores
  float* kbx = (float*)ws;    ws += (size_t)B * C * MAXDET * 16;       // boxes
  int*   cnt = (int*)ws;      ws += (size_t)B * C * 4;                 // alive counts
  float* cscore = (float*)ws; ws += (size_t)B * C * N * 4;             // compacted scores
  int*   cidx = (int*)ws;                                              // compacted idx

  compact_kernel<512><<<dim3(B * C), dim3(512), 0, stream>>>(
      cls, cnt, cscore, cidx, N, C);
  nms_kernel<16, 512><<<dim3(B * C), dim3(512), 0, stream>>>(
      boxes, cnt, cscore, cidx, ksc, kbx, N, C);
  nms_fallback_kernel<1024><<<dim3(B * C), dim3(1024), 0, stream>>>(
      boxes, cnt, cscore, cidx, ksc, kbx, N, C, 16 * 512);
  topk_kernel<<<dim3(B), dim3(64), 0, stream>>>(ksc, kbx, (float*)d_out, B, C);
}

// Round 3
// 365.426 us; speedup vs baseline: 1.9878x; 1.2755x over previous
//
#include <hip/hip_runtime.h>
#include <hip/hip_bf16.h>
#include <float.h>
#include <stdint.h>

// Forbid FMA contraction: reference (numpy fp32) rounds every mul/add
// separately; a fused (a1+a2)-iw*ih could flip an iou>0.5 decision.
#pragma clang fp contract(off)

#define NEGV   (-1e9f)
#define THRV   (0.05f)
#define MAXDET 100
#define LCAP   4000   // boxes cached in LDS (64KB static limit safety)

__device__ __forceinline__ void amax2(float& v, int& i, float ov, int oi) {
  // lexicographic: higher value wins; equal value -> lower index wins
  if (ov > v || (ov == v && oi < i)) { v = ov; i = oi; }
}

// monotone float->u32 map (total order preserved)
__device__ __forceinline__ unsigned mapf(float v) {
  const unsigned u = __float_as_uint(v);
  return (u & 0x80000000u) ? ~u : (u | 0x80000000u);
}
__device__ __forceinline__ float unmapf(unsigned m) {
  const unsigned u = (m & 0x80000000u) ? (m & 0x7FFFFFFFu) : ~m;
  return __uint_as_float(u);
}

// ---- DPP wave64 reductions (VALU pipe; no LDS, no ds_permute) -------------
// row_shr:1/2/4/8 then row_bcast15/31 accumulates the reduction into lane 63.
#define DPP_MAXF(v, CTRL) do {                                               \
    int _t = __builtin_amdgcn_update_dpp(__float_as_int(v), __float_as_int(v),\
                                         CTRL, 0xF, 0xF, false);             \
    (v) = fmaxf((v), __int_as_float(_t)); } while (0)
#define DPP_MINU(v, CTRL) do {                                               \
    unsigned _t = (unsigned)__builtin_amdgcn_update_dpp((int)(v), (int)(v),  \
                                         CTRL, 0xF, 0xF, false);             \
    (v) = ((v) < _t ? (v) : _t); } while (0)

__device__ __forceinline__ float wave_fmax_b(float v) {
  DPP_MAXF(v, 0x111); DPP_MAXF(v, 0x112); DPP_MAXF(v, 0x114); DPP_MAXF(v, 0x118);
  DPP_MAXF(v, 0x142); DPP_MAXF(v, 0x143);
  return __int_as_float(__builtin_amdgcn_readlane(__float_as_int(v), 63));
}
__device__ __forceinline__ unsigned wave_umin_b(unsigned v) {
  DPP_MINU(v, 0x111); DPP_MINU(v, 0x112); DPP_MINU(v, 0x114); DPP_MINU(v, 0x118);
  DPP_MINU(v, 0x142); DPP_MINU(v, 0x143);
  return (unsigned)__builtin_amdgcn_readlane((int)v, 63);
}

// ---------------------------------------------------------------------------
// Kernel 1: per-(image,class) stable compaction of scores > 0.05.
// Order-preserving => compacted position order == original index order,
// so downstream tie-breaks on compacted position match jnp.argmax.
// ---------------------------------------------------------------------------
template<int BT>
__global__ __launch_bounds__(BT, 1) void compact_kernel(
    const float* __restrict__ cls, int* __restrict__ cnt,
    float* __restrict__ cscore, int* __restrict__ cidx, int N, int C)
{
  const int bc = blockIdx.x;
  const int b = bc / C, c = bc % C;
  const int tid = threadIdx.x, lane = tid & 63, wid = tid >> 6;
  const int chunk = (N + BT - 1) / BT;
  const int i0 = tid * chunk;
  const int i1 = min(N, i0 + chunk);
  const float* cp = cls + (size_t)b * N * C + c;

  int cntt = 0;
  for (int i = i0; i < i1; ++i) cntt += (cp[(size_t)i * C] > THRV) ? 1 : 0;

  int inc = cntt;
#pragma unroll
  for (int off = 1; off < 64; off <<= 1) {
    const int u = __shfl_up(inc, off, 64);
    if (lane >= off) inc += u;
  }
  __shared__ int wtot[BT / 64];
  if (lane == 63) wtot[wid] = inc;
  __syncthreads();
  int base = 0;
  for (int w = 0; w < wid; ++w) base += wtot[w];
  int pos = base + inc - cntt;

  for (int i = i0; i < i1; ++i) {
    const float s = cp[(size_t)i * C];
    if (s > THRV) {
      cscore[(size_t)bc * N + pos] = s;
      cidx[(size_t)bc * N + pos] = i;
      ++pos;
    }
  }
  if (tid == BT - 1) cnt[bc] = base + inc;
}

// ---------------------------------------------------------------------------
// Kernel 2: register-resident greedy NMS, 1 barrier/iter, DPP reductions.
// One block per (image,class); handles cn <= KM*BT (else fallback kernel).
// ---------------------------------------------------------------------------
template<int KM, int BT>
__global__ __launch_bounds__(BT, 1) void nms_kernel(
    const float* __restrict__ boxes, const int* __restrict__ cnt,
    const float* __restrict__ cscore, const int* __restrict__ cidx,
    float* __restrict__ ksc, float* __restrict__ kbx, int N, int C)
{
#pragma clang fp contract(off)
  const int bc = blockIdx.x;
  const int cn = cnt[bc];
  if (cn > KM * BT) return;           // fallback kernel owns this block
  const int b = bc / C;
  const int tid = threadIdx.x, lane = tid & 63, wid = tid >> 6;
  constexpr int NW = BT / 64;

  float sc[KM], px1[KM], py1[KM], px2[KM], py2[KM], ar[KM];
  const float* bb = boxes + (size_t)b * N * 4;
  const float* cs = cscore + (size_t)bc * N;
  const int*   ci = cidx   + (size_t)bc * N;

  __shared__ float4 lbox[LCAP];                 // box table (winner fetch)
  __shared__ unsigned long long red[2][NW];     // ping-pong wave results

  float bv = NEGV; int bi = 0x7FFFFFFF;
#pragma unroll
  for (int k = 0; k < KM; ++k) {
    const int p = tid + k * BT;
    sc[k] = NEGV; px1[k] = 0.f; py1[k] = 0.f; px2[k] = 0.f; py2[k] = 0.f;
    ar[k] = 0.f;
    if (p < cn) {
      const float s = cs[p];
      const int id = ci[p];
      const float4 v = *reinterpret_cast<const float4*>(bb + (size_t)id * 4);
      sc[k] = s; px1[k] = v.x; py1[k] = v.y; px2[k] = v.z; py2[k] = v.w;
      ar[k] = (v.z - v.x) * (v.w - v.y);
      if (p < LCAP) lbox[p] = v;
      if (s > bv) { bv = s; bi = p; }   // p ascending in k => first-max
    }
  }

  float* ko  = ksc + (size_t)bc * MAXDET;
  float* kbo = kbx + (size_t)bc * MAXDET * 4;

  for (int m = 0; m < MAXDET; ++m) {
    // --- in-wave DPP argmax: max value then min index among maxima ---
    const float wmax = wave_fmax_b(bv);
    const unsigned wbi =
        wave_umin_b((bv == wmax) ? (unsigned)bi : 0xFFFFFFFFu);
    if (lane == 0)
      red[m & 1][wid] = ((unsigned long long)mapf(wmax) << 32) | ~wbi;
    __syncthreads();   // the only barrier per iteration (also fences lbox init)
    unsigned long long best = red[m & 1][0];
#pragma unroll
    for (int w = 1; w < NW; ++w) {
      const unsigned long long o = red[m & 1][w];
      if (o > best) best = o;          // (value desc, index asc) by packing
    }
    const float gv = unmapf((unsigned)(best >> 32));
    const int   gi = (int)(~(unsigned)best);

    if (gv <= THRV) {                  // uniform: nothing valid remains
      for (int mm = m + tid; mm < MAXDET; mm += BT) {
        ko[mm] = NEGV;
        kbo[mm * 4 + 0] = 0.f; kbo[mm * 4 + 1] = 0.f;
        kbo[mm * 4 + 2] = 0.f; kbo[mm * 4 + 3] = 0.f;
      }
      return;
    }
    // --- fetch winner box: LDS broadcast (common) or global (rare tail) ---
    float4 q;
    if (gi < LCAP) {
      q = lbox[gi];
    } else {
      const int id = ci[gi];
      q = *reinterpret_cast<const float4*>(bb + (size_t)id * 4);
    }
    const float qx1 = q.x, qy1 = q.y, qx2 = q.z, qy2 = q.w;
    const float a1 = (qx2 - qx1) * (qy2 - qy1);
    if (tid == 0) {
      ko[m] = gv;
      kbo[m * 4 + 0] = qx1; kbo[m * 4 + 1] = qy1;
      kbo[m * 4 + 2] = qx2; kbo[m * 4 + 3] = qy2;
    }
    // --- fused suppress + next local argmax ---
    // sure-kill: 2*inter > den*(1+1e-5); sure-keep: 2*inter < den*(1-1e-5);
    // window -> exact IEEE divide fixup (bit-identical to reference).
    bv = NEGV; bi = 0x7FFFFFFF;
    unsigned amb = 0;
#pragma unroll
    for (int k = 0; k < KM; ++k) {
      if (k * BT < cn) {
        const int p = tid + k * BT;
        const float iw = fminf(qx2, px2[k]) - fmaxf(qx1, px1[k]);
        const float ih = fminf(qy2, py2[k]) - fmaxf(qy1, py1[k]);
        const bool ov = (iw > 0.f) && (ih > 0.f) && (p < cn);
        const float inter = ov ? iw * ih : 0.f;
        const float den = fmaxf((a1 + ar[k]) - inter, 1e-8f);
        const float i2 = inter + inter;
        const bool kill = i2 > den * 1.00001f;
        if (ov && !kill && (i2 > den * 0.99999f)) amb |= 1u << k;
        if (kill) sc[k] = NEGV;
        if (sc[k] > bv) { bv = sc[k]; bi = p; }
      }
    }
    if (__builtin_expect(__any(amb != 0), 0)) {
      // exact reference recompute for ambiguous slots
#pragma unroll
      for (int k = 0; k < KM; ++k) {
        if ((k * BT < cn) && ((amb >> k) & 1u)) {
          const float ix1 = fmaxf(qx1, px1[k]);
          const float iy1 = fmaxf(qy1, py1[k]);
          const float ix2 = fminf(qx2, px2[k]);
          const float iy2 = fminf(qy2, py2[k]);
          const float iw = fmaxf(ix2 - ix1, 0.f);
          const float ih = fmaxf(iy2 - iy1, 0.f);
          const float inter = iw * ih;
          const float den = fmaxf((a1 + ar[k]) - inter, 1e-8f);
          if ((inter / den) > 0.5f) sc[k] = NEGV;
        }
      }
      bv = NEGV; bi = 0x7FFFFFFF;
#pragma unroll
      for (int k = 0; k < KM; ++k) {
        if (k * BT < cn) {
          const int p = tid + k * BT;
          if (p < cn && sc[k] > bv) { bv = sc[k]; bi = p; }
        }
      }
    }
  }
}

// ---------------------------------------------------------------------------
// Kernel 2b: global-resident fallback for cn > cap (safety net; never runs
// at bench shapes).
// ---------------------------------------------------------------------------
template<int BT>
__global__ __launch_bounds__(BT, 1) void nms_fallback_kernel(
    const float* __restrict__ boxes, const int* __restrict__ cnt,
    float* __restrict__ cscore, const int* __restrict__ cidx,
    float* __restrict__ ksc, float* __restrict__ kbx, int N, int C, int cap)
{
#pragma clang fp contract(off)
  const int bc = blockIdx.x;
  const int cn = cnt[bc];
  if (cn <= cap) return;
  const int b = bc / C;
  const int tid = threadIdx.x, lane = tid & 63, wid = tid >> 6;
  constexpr int NW = BT / 64;
  const float* bb = boxes + (size_t)b * N * 4;
  float* cs = cscore + (size_t)bc * N;
  const int* ci = cidx + (size_t)bc * N;
  __shared__ unsigned long long red[NW];
  float* ko  = ksc + (size_t)bc * MAXDET;
  float* kbo = kbx + (size_t)bc * MAXDET * 4;

  for (int m = 0; m < MAXDET; ++m) {
    float bv = NEGV; int bi = 0x7FFFFFFF;
    for (int p = tid; p < cn; p += BT) {
      const float s = cs[p];
      if (s > bv) { bv = s; bi = p; }
    }
    const float wmax = wave_fmax_b(bv);
    const unsigned wbi =
        wave_umin_b((bv == wmax) ? (unsigned)bi : 0xFFFFFFFFu);
    if (lane == 0)
      red[wid] = ((unsigned long long)mapf(wmax) << 32) | ~wbi;
    __syncthreads();
    unsigned long long best = red[0];
#pragma unroll
    for (int w = 1; w < NW; ++w) {
      const unsigned long long o = red[w];
      if (o > best) best = o;
    }
    const float gv = unmapf((unsigned)(best >> 32));
    const int   gi = (int)(~(unsigned)best);
    __syncthreads();                   // WAR fence for red

    if (gv <= THRV) {
      for (int mm = m + tid; mm < MAXDET; mm += BT) {
        ko[mm] = NEGV;
        kbo[mm * 4 + 0] = 0.f; kbo[mm * 4 + 1] = 0.f;
        kbo[mm * 4 + 2] = 0.f; kbo[mm * 4 + 3] = 0.f;
      }
      return;
    }
    const int qid = ci[gi];
    const float4 q = *reinterpret_cast<const float4*>(bb + (size_t)qid * 4);
    const float a1 = (q.z - q.x) * (q.w - q.y);
    if (tid == 0) {
      ko[m] = gv;
      kbo[m * 4 + 0] = q.x; kbo[m * 4 + 1] = q.y;
      kbo[m * 4 + 2] = q.z; kbo[m * 4 + 3] = q.w;
    }
    for (int p = tid; p < cn; p += BT) {
      const float s = cs[p];
      if (s > NEGV) {
        const int id = ci[p];
        const float4 v = *reinterpret_cast<const float4*>(bb + (size_t)id * 4);
        const float ix1 = fmaxf(q.x, v.x);
        const float iy1 = fmaxf(q.y, v.y);
        const float ix2 = fminf(q.z, v.z);
        const float iy2 = fminf(q.w, v.w);
        const float iw = fmaxf(ix2 - ix1, 0.f);
        const float ih = fmaxf(iy2 - iy1, 0.f);
        const float inter = iw * ih;
        const float a2 = (v.z - v.x) * (v.w - v.y);
        const float den = fmaxf((a1 + a2) - inter, 1e-8f);
        if ((inter + inter) > den) {   // window handled exactly below
          if ((inter / den) > 0.5f) cs[p] = NEGV; else cs[p] = s;
        } else if ((inter / den) > 0.5f) cs[p] = NEGV;
      }
    }
  }
}

// ---------------------------------------------------------------------------
// Kernel 3: per-image top-100 = 80-way merge of per-class descending lists.
// Single wave, DPP reduces, LDS-resident score slab, deferred box gather.
// ---------------------------------------------------------------------------
__global__ __launch_bounds__(64, 1) void topk_kernel(
    const float* __restrict__ ksc, const float* __restrict__ kbx,
    float* __restrict__ out, int B, int C)
{
  const int b = blockIdx.x;
  const int lane = threadIdx.x;
  const int T = C * MAXDET;
  const float* s0 = ksc + (size_t)b * T;
  float* ob = out;                              // [B][100][4]
  float* os = out + (size_t)B * MAXDET * 4;     // [B][100]
  float* ol = os + (size_t)B * MAXDET;          // [B][100] labels as float

  __shared__ float ssc[8192];
  __shared__ int   wfi[MAXDET];
  __shared__ float wsc[MAXDET];
  const bool uselds = (T <= 8192);
  if (uselds)
    for (int i = lane; i < T; i += 64) ssc[i] = s0[i];
  __syncthreads();

  int h0 = 0, h1 = 0;
  const int c0 = lane;
  const int c1 = lane + 64;

  for (int m = 0; m < MAXDET; ++m) {
    float bv = -FLT_MAX; int bf = 0x7FFFFFFF;
    if (c0 < C && h0 < MAXDET) {
      const int f = c0 * MAXDET + h0;
      amax2(bv, bf, uselds ? ssc[f] : s0[f], f);
    }
    if (c1 < C && h1 < MAXDET) {
      const int f = c1 * MAXDET + h1;
      amax2(bv, bf, uselds ? ssc[f] : s0[f], f);
    }
    const float gmax = wave_fmax_b(bv);
    if (gmax <= THRV) {
      for (int mm = m + lane; mm < MAXDET; mm += 64) wfi[mm] = -1;
      break;
    }
    const unsigned gf =
        wave_umin_b((bv == gmax) ? (unsigned)bf : 0xFFFFFFFFu);
    const int wc = (int)gf / MAXDET;
    if (lane == (wc & 63)) { if (wc == c0) ++h0; else ++h1; }
    if (lane == 0) { wfi[m] = (int)gf; wsc[m] = gmax; }
  }
  __syncthreads();

  // parallel gather of winner boxes / labels
  for (int e = lane; e < MAXDET; e += 64) {
    const int f = wfi[e];
    float* od = ob + ((size_t)b * MAXDET + e) * 4;
    if (f < 0) {
      od[0] = -1.f; od[1] = -1.f; od[2] = -1.f; od[3] = -1.f;
      os[(size_t)b * MAXDET + e] = -1.f;
      ol[(size_t)b * MAXDET + e] = -1.f;
    } else {
      const float* bp = kbx + ((size_t)b * T + f) * 4;
      od[0] = bp[0]; od[1] = bp[1]; od[2] = bp[2]; od[3] = bp[3];
      os[(size_t)b * MAXDET + e] = wsc[e];
      ol[(size_t)b * MAXDET + e] = (float)(f / MAXDET);
    }
  }
}

extern "C" void kernel_launch(void* const* d_in, const int* in_sizes, int n_in,
                              void* d_out, int out_size, void* d_ws, size_t ws_size,
                              hipStream_t stream) {
  const float* boxes = (const float*)d_in[0];  // (B, N, 4) f32
  const float* cls   = (const float*)d_in[1];  // (B, N, C) f32
  const int B = out_size / (MAXDET * 6);       // 4 box + 1 score + 1 label
  const int N = in_sizes[0] / (B * 4);
  const int C = in_sizes[1] / (B * N);

  char* ws = (char*)d_ws;
  float* ksc = (float*)ws;    ws += (size_t)B * C * MAXDET * 4;        // scores
  float* kbx = (float*)ws;    ws += (size_t)B * C * MAXDET * 16;       // boxes
  int*   cnt = (int*)ws;      ws += (size_t)B * C * 4;                 // alive counts
  float* cscore = (float*)ws; ws += (size_t)B * C * N * 4;             // compacted scores
  int*   cidx = (int*)ws;                                              // compacted idx

  compact_kernel<512><<<dim3(B * C), dim3(512), 0, stream>>>(
      cls, cnt, cscore, cidx, N, C);
  nms_kernel<16, 512><<<dim3(B * C), dim3(512), 0, stream>>>(
      boxes, cnt, cscore, cidx, ksc, kbx, N, C);
  nms_fallback_kernel<1024><<<dim3(B * C), dim3(1024), 0, stream>>>(
      boxes, cnt, cscore, cidx, ksc, kbx, N, C, 16 * 512);
  topk_kernel<<<dim3(B), dim3(64), 0, stream>>>(ksc, kbx, (float*)d_out, B, C);
}